// Round 4
// baseline (695.468 us; speedup 1.0000x reference)
//
#include <hip/hip_runtime.h>
#include <hip/hip_bf16.h>

// Problem constants (from reference):
#define DIMV 2048   // dim
#define DIV  2048   // d_inner
#define BV   4
#define TV   4096
#define MV   (BV * TV)   // 16384 rows for both GEMMs
#define GK   2048        // K for both GEMMs
#define NCH  64          // scan chunks
#define CH   64          // scan chunk length (NCH*CH == TV)

typedef __bf16 bf16x8 __attribute__((ext_vector_type(8)));
typedef __bf16 bf16x4 __attribute__((ext_vector_type(4)));
typedef float  floatx4 __attribute__((ext_vector_type(4)));

__device__ __forceinline__ void gload_lds16(const void* g, void* l) {
    __builtin_amdgcn_global_load_lds((const __attribute__((address_space(1))) void*)g,
                                     (__attribute__((address_space(3))) void*)l,
                                     16, 0, 0);
}

// ---------------- fused fp32 -> bf16 conversion (x, W_in, W_out) ----------
__global__ __launch_bounds__(256) void cvt_all(const float4* __restrict__ x,
                                               const float4* __restrict__ wi,
                                               const float4* __restrict__ wo,
                                               ushort4* __restrict__ xb,
                                               ushort4* __restrict__ wib,
                                               ushort4* __restrict__ wob) {
    int i = blockIdx.x * 256 + threadIdx.x;
    const float4* src;
    ushort4* dst;
    int off;
    if (i < 8388608)       { src = x;  dst = xb;  off = 0; }
    else if (i < 9437184)  { src = wi; dst = wib; off = 8388608; }
    else                   { src = wo; dst = wob; off = 9437184; }
    float4 v = src[i - off];
    __hip_bfloat16 a = __float2bfloat16(v.x);
    __hip_bfloat16 b = __float2bfloat16(v.y);
    __hip_bfloat16 c = __float2bfloat16(v.z);
    __hip_bfloat16 d = __float2bfloat16(v.w);
    ushort4 o;
    o.x = *(unsigned short*)&a;
    o.y = *(unsigned short*)&b;
    o.z = *(unsigned short*)&c;
    o.w = *(unsigned short*)&d;
    dst[i - off] = o;
}

// ---------------- bf16 GEMM, B-transposed, 256x256 tile, 8-phase pipeline -
// C[m][n] = sum_k A[m][k] * Bt[n][k]; M=16384, N=2048, K=2048.
// 512 threads = 8 waves (2 M x 4 N); per wave 128x64 output = acc[8][4].
// LDS per matrix: [2 buf][2 half][128 rows][64 cols] bf16 = 64 KiB (128 tot).
// T2 swizzle (full 3-bit): phys = row*128 + (col_byte ^ ((row&7)<<4));
// global_load_lds source column inverse-permuted (rule #21). Conflicts = 0
// (verified round 3).
// ONE-PHASE-EARLY register pipeline: ds_reads feeding QUAD(p+1) are issued
// in phase p BEFORE phase p's MFMA cluster; no explicit lgkmcnt — the loads
// are compiler-visible so precise laddered lgkm waits are emitted, and the
// read latency hides under a full MFMA window. Balanced reads 4/8/8/4.
// Counted wait: single VMW(2) per K-tile at ph1-end (waits only on loads
// issued one full tile earlier; newest 2 stay in flight). Staging of tile
// t+2 into the buffer being read, one phase after each region's consuming
// QUAD (all-waves barrier in between). vmcnt never drains in steady state.
template <int EPI>
__global__ __launch_bounds__(512, 2) void gemm256_bt(const __hip_bfloat16* __restrict__ A,
                                                     const __hip_bfloat16* __restrict__ Bt,
                                                     float* __restrict__ Cf,
                                                     __hip_bfloat16* __restrict__ Cb) {
    __shared__ __align__(16) char AsB[65536];   // 2 buf x 2 half x 16 KiB
    __shared__ __align__(16) char BsB[65536];

    const int tid  = threadIdx.x;
    const int lane = tid & 63;
    const int wave = tid >> 6;
    const int wmh  = wave >> 2;          // A half (0/1); wm = wmh*128
    const int wnh  = (wave >> 1) & 1;    // B half
    const int wno  = wave & 1;           // 64-row block within B half
    const int lr   = lane & 15;
    const int lq   = lane >> 4;

    // T1: XCD-aware swizzle. 512 blocks, 8 XCDs, bijective (512 % 8 == 0).
    const int p   = blockIdx.y * gridDim.x + blockIdx.x;
    const int swz = (p & 7) * 64 + (p >> 3);
    const int m0  = (swz >> 3) * 256;
    const int n0  = (swz & 7) * 256;

    // Swizzled fragment-read offsets within a 16 KiB half-tile:
    // logical (row = mi*16+lr, col_byte = s*64 + lq*16); row&7 == lr&7.
    // phys = mi*2048 + lr*128 + ((s*64 + lq*16) ^ ((lr&7)<<4)).
    const int rdswz = lr * 128 + ((lq * 16) ^ ((lr & 7) << 4));
    const int rds[2] = { rdswz, rdswz ^ 64 };     // s=0 / s=1 (bit6 flip)
    const char* aRd0 = AsB + wmh * 16384;
    const char* bRd0 = BsB + wnh * 16384 + wno * 8192;

    // Staging source (inverse-swizzled global column): dest byte D = tid*16
    // within an 8192-B segment covers row = tid>>3, phys-in-row (tid&7)*16;
    // the logical data that belongs there is col ((tid&7)^(row&7))*16 B.
    const int srow = tid >> 3;                       // row within 64-row seg
    const int scol = ((tid & 7) ^ (srow & 7)) * 8;   // bf16 col within K-tile
    const __hip_bfloat16* aS_h0g0 = A  + (size_t)(m0 +   0 +  0 + srow) * GK + scol;
    const __hip_bfloat16* aS_h0g1 = A  + (size_t)(m0 +   0 + 64 + srow) * GK + scol;
    const __hip_bfloat16* aS_h1g0 = A  + (size_t)(m0 + 128 +  0 + srow) * GK + scol;
    const __hip_bfloat16* aS_h1g1 = A  + (size_t)(m0 + 128 + 64 + srow) * GK + scol;
    const __hip_bfloat16* bS_h0g0 = Bt + (size_t)(n0 +   0 +  0 + srow) * GK + scol;
    const __hip_bfloat16* bS_h0g1 = Bt + (size_t)(n0 +   0 + 64 + srow) * GK + scol;
    const __hip_bfloat16* bS_h1g0 = Bt + (size_t)(n0 + 128 +  0 + srow) * GK + scol;
    const __hip_bfloat16* bS_h1g1 = Bt + (size_t)(n0 + 128 + 64 + srow) * GK + scol;

#define BARR  asm volatile("s_barrier" ::: "memory")
#define VMW(N_) asm volatile("s_waitcnt vmcnt(" #N_ ")" ::: "memory")

#define STG(SRC_, DST_, T_) gload_lds16((SRC_) + (size_t)(T_) * 64, (DST_))
#define ST_AG0(T_, C_) do {                                                    \
    STG(aS_h0g0, AsB + (C_) * 32768 +     0 + tid * 16, T_);                   \
    STG(aS_h1g0, AsB + (C_) * 32768 + 16384 + tid * 16, T_); } while (0)
#define ST_AG1(T_, C_) do {                                                    \
    STG(aS_h0g1, AsB + (C_) * 32768 +  8192 + tid * 16, T_);                   \
    STG(aS_h1g1, AsB + (C_) * 32768 + 24576 + tid * 16, T_); } while (0)
#define ST_BG0(T_, C_) do {                                                    \
    STG(bS_h0g0, BsB + (C_) * 32768 +     0 + tid * 16, T_);                   \
    STG(bS_h1g0, BsB + (C_) * 32768 + 16384 + tid * 16, T_); } while (0)
#define ST_BG1(T_, C_) do {                                                    \
    STG(bS_h0g1, BsB + (C_) * 32768 +  8192 + tid * 16, T_);                   \
    STG(bS_h1g1, BsB + (C_) * 32768 + 24576 + tid * 16, T_); } while (0)

#define RDPH_A(DST_, MI0_, C_)                                                 \
    _Pragma("unroll") for (int mi_ = 0; mi_ < 4; ++mi_)                        \
      _Pragma("unroll") for (int s_ = 0; s_ < 2; ++s_)                         \
        DST_[mi_][s_] = *(const bf16x8*)(aRd0 + (C_) * 32768 +                 \
                                         ((MI0_) + mi_) * 2048 + rds[s_]);
#define RDPH_B(DST_, NI0_, C_)                                                 \
    _Pragma("unroll") for (int ni_ = 0; ni_ < 2; ++ni_)                        \
      _Pragma("unroll") for (int s_ = 0; s_ < 2; ++s_)                         \
        DST_[ni_][s_] = *(const bf16x8*)(bRd0 + (C_) * 32768 +                 \
                                         ((NI0_) + ni_) * 2048 + rds[s_]);

#define QUAD(MI0_, NI0_, AF_, BF_)                                             \
    __builtin_amdgcn_s_setprio(1);                                             \
    _Pragma("unroll") for (int mi_ = 0; mi_ < 4; ++mi_)                        \
      _Pragma("unroll") for (int ni_ = 0; ni_ < 2; ++ni_)                      \
        _Pragma("unroll") for (int s_ = 0; s_ < 2; ++s_)                       \
          acc[(MI0_) + mi_][(NI0_) + ni_] =                                    \
            __builtin_amdgcn_mfma_f32_16x16x32_bf16(                           \
              AF_[mi_][s_], BF_[ni_][s_],                                      \
              acc[(MI0_) + mi_][(NI0_) + ni_], 0, 0, 0);                       \
    __builtin_amdgcn_s_setprio(0);

// One K-tile = 4 phases, one-phase-early reads (balanced 4/8/8/4):
//   ph0: rd b23(t)           -> QUAD0(a03,b01)   [a03,b01 read last tile]
//   ph1: stage AG0(t+2), rd a47(t) -> QUAD1(a03,b23); VMW(2)
//   ph2: stage BG0+BG1(t+2), rd a03(t+1) [buf^1] -> QUAD2(a47,b23)
//   ph3: stage AG1(t+2), rd b01n(t+1) [buf^1]    -> QUAD3(a47,b01)
// Region safety: every segment is staged one phase after its consuming
// QUAD (all-waves barrier in between). Cross-tile reads at ph2/ph3 need
// tile t+1 resident: guaranteed by VMW(2)+BARR at ph1-end (waits on loads
// issued one full tile earlier; leaves the 2 newest in flight).
// MODE: 1 steady; 2 = tile 30 (no stage, VMW(0) @ph1, keeps read-ahead);
//       3 = tile 31 (no stage, no vmw, no read-ahead).
#define KTILE(T_, C_, MODE_, B01C_, B01N_) do {                                \
    /* ---- phase 0 ---- */                                                    \
    RDPH_B(b23, 2, C_);                                                        \
    BARR;                                                                      \
    QUAD(0, 0, a03, B01C_);                                                    \
    BARR;                                                                      \
    /* ---- phase 1 ---- */                                                    \
    if ((MODE_) == 1) { ST_AG0((T_) + 2, C_); }                                \
    RDPH_A(a47, 4, C_);                                                        \
    BARR;                                                                      \
    QUAD(0, 2, a03, b23);                                                      \
    if ((MODE_) == 1) { VMW(2); }                                              \
    if ((MODE_) == 2) { VMW(0); }                                              \
    BARR;                                                                      \
    /* ---- phase 2 ---- */                                                    \
    if ((MODE_) == 1) { ST_BG0((T_) + 2, C_); ST_BG1((T_) + 2, C_); }          \
    if ((MODE_) != 3) { RDPH_A(a03, 0, (C_) ^ 1); }                            \
    BARR;                                                                      \
    QUAD(4, 2, a47, b23);                                                      \
    BARR;                                                                      \
    /* ---- phase 3 ---- */                                                    \
    if ((MODE_) == 1) { ST_AG1((T_) + 2, C_); }                                \
    if ((MODE_) != 3) { RDPH_B(B01N_, 0, (C_) ^ 1); }                          \
    BARR;                                                                      \
    QUAD(4, 0, a47, B01C_);                                                    \
    BARR;                                                                      \
} while (0)

    floatx4 acc[8][4];
#pragma unroll
    for (int i = 0; i < 8; ++i)
#pragma unroll
        for (int j = 0; j < 4; ++j) acc[i][j] = 0.f;

    bf16x8 a03[4][2], a47[4][2], b23[2][2], b01a[2][2], b01b[2][2];

    // Prologue: tiles 0 and 1 fully staged (16 loads). VMW(8): tile 0
    // landed, tile 1's 8 in flight. Then issue Q0(t0)'s reads.
    ST_AG0(0, 0); ST_BG0(0, 0); ST_BG1(0, 0); ST_AG1(0, 0);
    ST_AG0(1, 1); ST_BG0(1, 1); ST_BG1(1, 1); ST_AG1(1, 1);
    VMW(8); BARR;
    RDPH_A(a03, 0, 0);
    RDPH_B(b01a, 0, 0);

    for (int t2 = 0; t2 < 15; ++t2) {        // tiles 0..29 steady-state
        KTILE(2 * t2,     0, 1, b01a, b01b);
        KTILE(2 * t2 + 1, 1, 1, b01b, b01a);
    }
    KTILE(30, 0, 2, b01a, b01b);              // drain @ph1, read-ahead t31
    KTILE(31, 1, 3, b01b, b01a);              // final tile

#undef KTILE
#undef QUAD
#undef RDPH_A
#undef RDPH_B
#undef ST_AG0
#undef ST_AG1
#undef ST_BG0
#undef ST_BG1
#undef STG
#undef VMW
#undef BARR

    // Epilogue. C/D layout: col = lane&15, row = quad*4 + reg.
    const int wm = wmh * 128;
    const int wn = (wave & 3) * 64;
#pragma unroll
    for (int mi = 0; mi < 8; ++mi) {
#pragma unroll
        for (int r = 0; r < 4; ++r) {
            const int row = m0 + wm + mi * 16 + lq * 4 + r;
#pragma unroll
            for (int ni = 0; ni < 4; ++ni) {
                const int col = n0 + wn + ni * 16 + lr;
                float v = acc[mi][ni][r];
                if (EPI == 1) {
                    float s = v / (1.f + __expf(-v));   // silu
                    Cb[(size_t)row * DIV + col] = __float2bfloat16(s);
                } else {
                    Cf[(size_t)row * DIMV + col] = v;
                }
            }
        }
    }
}

// ---------------- scan pass 1: per-chunk carries (4 e-channels/thread) ----
__global__ __launch_bounds__(256) void scan_carry(const __hip_bfloat16* __restrict__ xp,
                                                  const float* __restrict__ logd,
                                                  const float* __restrict__ bias,
                                                  float* __restrict__ carry) {
    const int eg = blockIdx.x * 256 + threadIdx.x;  // e-group (4 channels)
    const int e0 = eg * 4;
    const int c = blockIdx.y;
    const int b = blockIdx.z;
    const float4 ld = ((const float4*)logd)[eg];
    const float4 bb = ((const float4*)bias)[eg];
    float dv[4] = {1.f / (1.f + __expf(-ld.x)), 1.f / (1.f + __expf(-ld.y)),
                   1.f / (1.f + __expf(-ld.z)), 1.f / (1.f + __expf(-ld.w))};
    float bv[4] = {bb.x, bb.y, bb.z, bb.w};
    const __hip_bfloat16* p = xp + ((size_t)(b * TV + c * CH)) * DIV + e0;
    float h[4] = {0.f, 0.f, 0.f, 0.f};
#pragma unroll 8
    for (int i = 0; i < CH; ++i) {
        bf16x4 v = *(const bf16x4*)(p + (size_t)i * DIV);
#pragma unroll
        for (int j = 0; j < 4; ++j)
            h[j] = dv[j] * ((float)v[j] + h[j]) + bv[j];
    }
    float4 o = {h[0], h[1], h[2], h[3]};
    *(float4*)&carry[((size_t)b * NCH + c) * DIV + e0] = o;
}

// ---------------- scan pass 2: combine carries, emit cell + h_final -------
__global__ __launch_bounds__(256) void scan_apply(const __hip_bfloat16* __restrict__ xp,
                                                  const float* __restrict__ logd,
                                                  const float* __restrict__ bias,
                                                  const float* __restrict__ h0,
                                                  const float* __restrict__ carry,
                                                  __hip_bfloat16* __restrict__ cell,
                                                  float* __restrict__ hfin) {
    const int eg = blockIdx.x * 256 + threadIdx.x;
    const int e0 = eg * 4;
    const int c = blockIdx.y;
    const int b = blockIdx.z;
    const float4 ld = ((const float4*)logd)[eg];
    const float4 bb = ((const float4*)bias)[eg];
    float dv[4] = {1.f / (1.f + __expf(-ld.x)), 1.f / (1.f + __expf(-ld.y)),
                   1.f / (1.f + __expf(-ld.z)), 1.f / (1.f + __expf(-ld.w))};
    float bv[4] = {bb.x, bb.y, bb.z, bb.w};
    float dCH[4];
#pragma unroll
    for (int j = 0; j < 4; ++j) dCH[j] = __powf(dv[j], (float)CH);

    // H = true h at entry to chunk c (chunk-level recurrence over carries)
    float4 H4 = *(const float4*)&h0[(size_t)b * DIV + e0];
    float H[4] = {H4.x, H4.y, H4.z, H4.w};
    for (int j = 0; j < c; ++j) {
        float4 cr = *(const float4*)&carry[((size_t)b * NCH + j) * DIV + e0];
#pragma unroll
        for (int q = 0; q < 4; ++q) H[q] = dCH[q] * H[q] + ((const float*)&cr)[q];
    }

    const size_t base = ((size_t)(b * TV + c * CH)) * DIV + e0;
    float h[4] = {H[0], H[1], H[2], H[3]};
#pragma unroll 4
    for (int i = 0; i < CH; ++i) {
        bf16x4 v = *(const bf16x4*)(xp + base + (size_t)i * DIV);
        ushort4 o;
        unsigned short* op = (unsigned short*)&o;
#pragma unroll
        for (int j = 0; j < 4; ++j) {
            h[j] = dv[j] * ((float)v[j] + h[j]) + bv[j];
            float cv = h[j] * (h[j] / (1.f + __expf(-h[j])));   // h * silu(h)
            __hip_bfloat16 cb = __float2bfloat16(cv);
            op[j] = *(unsigned short*)&cb;
        }
        *(ushort4*)(cell + base + (size_t)i * DIV) = o;
    }
    if (c == NCH - 1) {
        float4 o = {h[0], h[1], h[2], h[3]};
        *(float4*)&hfin[(size_t)b * DIV + e0] = o;
    }
}

// -------------------------------------------------------------------------
extern "C" void kernel_launch(void* const* d_in, const int* in_sizes, int n_in,
                              void* d_out, int out_size, void* d_ws, size_t ws_size,
                              hipStream_t stream) {
    const float* x     = (const float*)d_in[0];   // [B,T,DIM]
    const float* h0    = (const float*)d_in[1];   // [B,DI]
    const float* W_in  = (const float*)d_in[2];   // [DI,DIM]
    const float* W_out = (const float*)d_in[3];   // [DIM,DI]
    const float* log_d = (const float*)d_in[4];   // [DI]
    const float* bias  = (const float*)d_in[5];   // [DI]

    float* out  = (float*)d_out;                       // [B,T,DIM] fp32
    float* hfin = out + (size_t)BV * TV * DIMV;        // [B,DI] fp32

    // Workspace layout (bytes):
    char* ws = (char*)d_ws;
    __hip_bfloat16* xb    = (__hip_bfloat16*)ws;                          // 64 MiB
    __hip_bfloat16* cellb = xb;                                           // alias: x dead after GEMM1
    __hip_bfloat16* wib   = (__hip_bfloat16*)(ws + 67108864);             // 8 MiB
    __hip_bfloat16* wob   = (__hip_bfloat16*)(ws + 67108864 + 8388608);   // 8 MiB
    __hip_bfloat16* xpb   = (__hip_bfloat16*)(ws + 67108864 + 16777216);  // 64 MiB
    float*          carry = (float*)(ws + 134217728 + 16777216);          // 2 MiB

    // 1) convert inputs to bf16 (single fused kernel)
    {
        int n4 = 10485760;   // 8388608 + 1048576 + 1048576 float4s
        cvt_all<<<n4 / 256, 256, 0, stream>>>((const float4*)x, (const float4*)W_in,
                                              (const float4*)W_out,
                                              (ushort4*)xb, (ushort4*)wib, (ushort4*)wob);
    }

    // 2) GEMM1: xp = silu(x @ W_in^T), bf16 out
    gemm256_bt<1><<<dim3(DIV / 256, MV / 256), 512, 0, stream>>>(xb, wib, nullptr, xpb);

    // 3) scan: chunk carries, then combine + emit cell (bf16) and h_final
    scan_carry<<<dim3(DIV / 1024, NCH, BV), 256, 0, stream>>>(xpb, log_d, bias, carry);
    scan_apply<<<dim3(DIV / 1024, NCH, BV), 256, 0, stream>>>(xpb, log_d, bias, h0, carry, cellb, hfin);

    // 4) GEMM2: out = cell @ W_out^T, fp32 out
    gemm256_bt<0><<<dim3(DIMV / 256, MV / 256), 512, 0, stream>>>(cellb, wob, out, nullptr);
}

// Round 5
// 556.161 us; speedup vs baseline: 1.2505x; 1.2505x over previous
//
#include <hip/hip_runtime.h>
#include <hip/hip_bf16.h>

// Problem constants (from reference):
#define DIMV 2048   // dim
#define DIV  2048   // d_inner
#define BV   4
#define TV   4096
#define MV   (BV * TV)   // 16384 rows for both GEMMs
#define GK   2048        // K for both GEMMs
#define NCH  64          // scan chunks
#define CH   64          // scan chunk length (NCH*CH == TV)

typedef __bf16 bf16x8 __attribute__((ext_vector_type(8)));
typedef __bf16 bf16x4 __attribute__((ext_vector_type(4)));
typedef float  floatx4 __attribute__((ext_vector_type(4)));

__device__ __forceinline__ void gload_lds16(const void* g, void* l) {
    __builtin_amdgcn_global_load_lds((const __attribute__((address_space(1))) void*)g,
                                     (__attribute__((address_space(3))) void*)l,
                                     16, 0, 0);
}

// ---------------- fused fp32 -> bf16 conversion (x, W_in, W_out) ----------
__global__ __launch_bounds__(256) void cvt_all(const float4* __restrict__ x,
                                               const float4* __restrict__ wi,
                                               const float4* __restrict__ wo,
                                               ushort4* __restrict__ xb,
                                               ushort4* __restrict__ wib,
                                               ushort4* __restrict__ wob) {
    int i = blockIdx.x * 256 + threadIdx.x;
    const float4* src;
    ushort4* dst;
    int off;
    if (i < 8388608)       { src = x;  dst = xb;  off = 0; }
    else if (i < 9437184)  { src = wi; dst = wib; off = 8388608; }
    else                   { src = wo; dst = wob; off = 9437184; }
    float4 v = src[i - off];
    __hip_bfloat16 a = __float2bfloat16(v.x);
    __hip_bfloat16 b = __float2bfloat16(v.y);
    __hip_bfloat16 c = __float2bfloat16(v.z);
    __hip_bfloat16 d = __float2bfloat16(v.w);
    ushort4 o;
    o.x = *(unsigned short*)&a;
    o.y = *(unsigned short*)&b;
    o.z = *(unsigned short*)&c;
    o.w = *(unsigned short*)&d;
    dst[i - off] = o;
}

// ---------------- bf16 GEMM, B-transposed, 256x256 tile ------------------
// C[m][n] = sum_k A[m][k] * Bt[n][k]; M=16384, N=2048, K=2048.
// 512 threads = 8 waves (2 M x 4 N); per wave 128x64 output = acc[8][4].
// LDS per matrix: [2 buf][2 half][128 rows][64 cols] bf16 = 64 KiB (128 tot).
// T2 swizzle (full 3-bit): phys = row*128 + (col_byte ^ ((row&7)<<4));
// global_load_lds source column inverse-permuted (rule #21). Conflicts = 0
// (verified round 3).
// Schedule (round 5): 4 phases/K-tile, THREE barriers/tile, no
// sched_barrier and no forced pre-MFMA lgkm drain — reads are
// compiler-visible, so the compiler ladders lgkmcnt before each MFMA and
// read latency hides under the MFMA cluster. One plain lgkmcnt(0) per
// read-phase sits AFTER the QUAD, guaranteeing no wave crosses the
// phase-end barrier with ds_reads in flight (overwrite safety for the
// next phase's staging). Region audit:
//   ph0-end barrier guards ST_AG0@ph1   (a03 region read @ph0)
//   ph1-end barrier guards ST_BG0/1@ph2 (b23 read @ph1, b01 read @ph0)
//   ph2-end barrier guards ST_AG1@ph3   (a47 read @ph2) + VMW invariant
//   ph3 needs no barrier (writes bufC AG1; next reads are bufC^1).
// ONE counted vmcnt per K-tile at ph2-end: VMW(6) = loads issued after
// tile t+1's last stage (t.ph1's 2 + t.ph2's 4) -> t+1 fully resident
// before its first read at t+1.ph0; tile t+2's stages stay in flight (T4).
template <int EPI>
__global__ __launch_bounds__(512, 2) void gemm256_bt(const __hip_bfloat16* __restrict__ A,
                                                     const __hip_bfloat16* __restrict__ Bt,
                                                     float* __restrict__ Cf,
                                                     __hip_bfloat16* __restrict__ Cb) {
    __shared__ __align__(16) char AsB[65536];   // 2 buf x 2 half x 16 KiB
    __shared__ __align__(16) char BsB[65536];

    const int tid  = threadIdx.x;
    const int lane = tid & 63;
    const int wave = tid >> 6;
    const int wmh  = wave >> 2;          // A half (0/1); wm = wmh*128
    const int wnh  = (wave >> 1) & 1;    // B half
    const int wno  = wave & 1;           // 64-row block within B half
    const int lr   = lane & 15;
    const int lq   = lane >> 4;

    // T1: XCD-aware swizzle. 512 blocks, 8 XCDs, bijective (512 % 8 == 0).
    const int p   = blockIdx.y * gridDim.x + blockIdx.x;
    const int swz = (p & 7) * 64 + (p >> 3);
    const int m0  = (swz >> 3) * 256;
    const int n0  = (swz & 7) * 256;

    // Swizzled fragment-read offsets within a 16 KiB half-tile:
    // logical (row = mi*16+lr, col_byte = s*64 + lq*16); row&7 == lr&7.
    // phys = mi*2048 + lr*128 + ((s*64 + lq*16) ^ ((lr&7)<<4)).
    const int rdswz = lr * 128 + ((lq * 16) ^ ((lr & 7) << 4));
    const int rds[2] = { rdswz, rdswz ^ 64 };     // s=0 / s=1 (bit6 flip)
    const char* aRd0 = AsB + wmh * 16384;
    const char* bRd0 = BsB + wnh * 16384 + wno * 8192;

    // Staging source (inverse-swizzled global column): dest byte D = tid*16
    // within an 8192-B segment covers row = tid>>3, phys-in-row (tid&7)*16;
    // the logical data that belongs there is col ((tid&7)^(row&7))*16 B.
    const int srow = tid >> 3;                       // row within 64-row seg
    const int scol = ((tid & 7) ^ (srow & 7)) * 8;   // bf16 col within K-tile
    const __hip_bfloat16* aS_h0g0 = A  + (size_t)(m0 +   0 +  0 + srow) * GK + scol;
    const __hip_bfloat16* aS_h0g1 = A  + (size_t)(m0 +   0 + 64 + srow) * GK + scol;
    const __hip_bfloat16* aS_h1g0 = A  + (size_t)(m0 + 128 +  0 + srow) * GK + scol;
    const __hip_bfloat16* aS_h1g1 = A  + (size_t)(m0 + 128 + 64 + srow) * GK + scol;
    const __hip_bfloat16* bS_h0g0 = Bt + (size_t)(n0 +   0 +  0 + srow) * GK + scol;
    const __hip_bfloat16* bS_h0g1 = Bt + (size_t)(n0 +   0 + 64 + srow) * GK + scol;
    const __hip_bfloat16* bS_h1g0 = Bt + (size_t)(n0 + 128 +  0 + srow) * GK + scol;
    const __hip_bfloat16* bS_h1g1 = Bt + (size_t)(n0 + 128 + 64 + srow) * GK + scol;

#define BARR  asm volatile("s_barrier" ::: "memory")
#define WAITL asm volatile("s_waitcnt lgkmcnt(0)" ::: "memory")
#define VMW(N_) asm volatile("s_waitcnt vmcnt(" #N_ ")" ::: "memory")

#define STG(SRC_, DST_, T_) gload_lds16((SRC_) + (size_t)(T_) * 64, (DST_))
#define ST_AG0(T_, C_) do {                                                    \
    STG(aS_h0g0, AsB + (C_) * 32768 +     0 + tid * 16, T_);                   \
    STG(aS_h1g0, AsB + (C_) * 32768 + 16384 + tid * 16, T_); } while (0)
#define ST_AG1(T_, C_) do {                                                    \
    STG(aS_h0g1, AsB + (C_) * 32768 +  8192 + tid * 16, T_);                   \
    STG(aS_h1g1, AsB + (C_) * 32768 + 24576 + tid * 16, T_); } while (0)
#define ST_BG0(T_, C_) do {                                                    \
    STG(bS_h0g0, BsB + (C_) * 32768 +     0 + tid * 16, T_);                   \
    STG(bS_h1g0, BsB + (C_) * 32768 + 16384 + tid * 16, T_); } while (0)
#define ST_BG1(T_, C_) do {                                                    \
    STG(bS_h0g1, BsB + (C_) * 32768 +  8192 + tid * 16, T_);                   \
    STG(bS_h1g1, BsB + (C_) * 32768 + 24576 + tid * 16, T_); } while (0)

#define RDPH_A(DST_, MI0_, C_)                                                 \
    _Pragma("unroll") for (int mi_ = 0; mi_ < 4; ++mi_)                        \
      _Pragma("unroll") for (int s_ = 0; s_ < 2; ++s_)                         \
        DST_[mi_][s_] = *(const bf16x8*)(aRd0 + (C_) * 32768 +                 \
                                         ((MI0_) + mi_) * 2048 + rds[s_]);
#define RDPH_B(DST_, NI0_, C_)                                                 \
    _Pragma("unroll") for (int ni_ = 0; ni_ < 2; ++ni_)                        \
      _Pragma("unroll") for (int s_ = 0; s_ < 2; ++s_)                         \
        DST_[ni_][s_] = *(const bf16x8*)(bRd0 + (C_) * 32768 +                 \
                                         ((NI0_) + ni_) * 2048 + rds[s_]);

#define QUAD(MI0_, NI0_, AF_, BF_)                                             \
    __builtin_amdgcn_s_setprio(1);                                             \
    _Pragma("unroll") for (int mi_ = 0; mi_ < 4; ++mi_)                        \
      _Pragma("unroll") for (int ni_ = 0; ni_ < 2; ++ni_)                      \
        _Pragma("unroll") for (int s_ = 0; s_ < 2; ++s_)                       \
          acc[(MI0_) + mi_][(NI0_) + ni_] =                                    \
            __builtin_amdgcn_mfma_f32_16x16x32_bf16(                           \
              AF_[mi_][s_], BF_[ni_][s_],                                      \
              acc[(MI0_) + mi_][(NI0_) + ni_], 0, 0, 0);                       \
    __builtin_amdgcn_s_setprio(0);

// One K-tile = 4 phases, 3 barriers. Reads 12/4/8/0, all consumed in their
// issue phase (compiler ladders lgkm waits into the QUAD).
// MODE: 1 steady; 2 = tile 30 (no stage, VMW(0) at ph2-end); 0 = tile 31.
#define KTILE(T_, C_, MODE_) do {                                              \
    bf16x8 a03[4][2], a47[4][2], b01[2][2], b23[2][2];                         \
    /* ---- phase 0 ---- */                                                    \
    RDPH_A(a03, 0, C_);                                                        \
    RDPH_B(b01, 0, C_);                                                        \
    QUAD(0, 0, a03, b01);                                                      \
    WAITL; BARR;                                                               \
    /* ---- phase 1 ---- */                                                    \
    if ((MODE_) == 1) { ST_AG0((T_) + 2, C_); }                                \
    RDPH_B(b23, 2, C_);                                                        \
    QUAD(0, 2, a03, b23);                                                      \
    WAITL; BARR;                                                               \
    /* ---- phase 2 ---- */                                                    \
    if ((MODE_) == 1) { ST_BG0((T_) + 2, C_); ST_BG1((T_) + 2, C_); }          \
    RDPH_A(a47, 4, C_);                                                        \
    QUAD(4, 2, a47, b23);                                                      \
    WAITL;                                                                     \
    if ((MODE_) == 1) { VMW(6); }                                              \
    if ((MODE_) == 2) { VMW(0); }                                              \
    BARR;                                                                      \
    /* ---- phase 3 (no barrier: writes bufC AG1; next reads bufC^1) ---- */   \
    if ((MODE_) == 1) { ST_AG1((T_) + 2, C_); }                                \
    QUAD(4, 0, a47, b01);                                                      \
} while (0)

    floatx4 acc[8][4];
#pragma unroll
    for (int i = 0; i < 8; ++i)
#pragma unroll
        for (int j = 0; j < 4; ++j) acc[i][j] = 0.f;

    // Prologue: tiles 0 and 1 fully staged (16 loads). VMW(8): tile 0
    // landed, tile 1's 8 in flight.
    ST_AG0(0, 0); ST_BG0(0, 0); ST_BG1(0, 0); ST_AG1(0, 0);
    ST_AG0(1, 1); ST_BG0(1, 1); ST_BG1(1, 1); ST_AG1(1, 1);
    VMW(8); BARR;

    for (int t2 = 0; t2 < 15; ++t2) {        // tiles 0..29 steady-state
        KTILE(2 * t2,     0, 1);
        KTILE(2 * t2 + 1, 1, 1);
    }
    KTILE(30, 0, 2);                          // no staging; drain at ph2
    KTILE(31, 1, 0);                          // final tile

#undef KTILE
#undef QUAD
#undef RDPH_A
#undef RDPH_B
#undef ST_AG0
#undef ST_AG1
#undef ST_BG0
#undef ST_BG1
#undef STG
#undef VMW
#undef WAITL
#undef BARR

    // Epilogue. C/D layout: col = lane&15, row = quad*4 + reg.
    const int wm = wmh * 128;
    const int wn = (wave & 3) * 64;
#pragma unroll
    for (int mi = 0; mi < 8; ++mi) {
#pragma unroll
        for (int r = 0; r < 4; ++r) {
            const int row = m0 + wm + mi * 16 + lq * 4 + r;
#pragma unroll
            for (int ni = 0; ni < 4; ++ni) {
                const int col = n0 + wn + ni * 16 + lr;
                float v = acc[mi][ni][r];
                if (EPI == 1) {
                    float s = v / (1.f + __expf(-v));   // silu
                    Cb[(size_t)row * DIV + col] = __float2bfloat16(s);
                } else {
                    Cf[(size_t)row * DIMV + col] = v;
                }
            }
        }
    }
}

// ---------------- scan pass 1: per-chunk carries (4 e-channels/thread) ----
__global__ __launch_bounds__(256) void scan_carry(const __hip_bfloat16* __restrict__ xp,
                                                  const float* __restrict__ logd,
                                                  const float* __restrict__ bias,
                                                  float* __restrict__ carry) {
    const int eg = blockIdx.x * 256 + threadIdx.x;  // e-group (4 channels)
    const int e0 = eg * 4;
    const int c = blockIdx.y;
    const int b = blockIdx.z;
    const float4 ld = ((const float4*)logd)[eg];
    const float4 bb = ((const float4*)bias)[eg];
    float dv[4] = {1.f / (1.f + __expf(-ld.x)), 1.f / (1.f + __expf(-ld.y)),
                   1.f / (1.f + __expf(-ld.z)), 1.f / (1.f + __expf(-ld.w))};
    float bv[4] = {bb.x, bb.y, bb.z, bb.w};
    const __hip_bfloat16* p = xp + ((size_t)(b * TV + c * CH)) * DIV + e0;
    float h[4] = {0.f, 0.f, 0.f, 0.f};
#pragma unroll 8
    for (int i = 0; i < CH; ++i) {
        bf16x4 v = *(const bf16x4*)(p + (size_t)i * DIV);
#pragma unroll
        for (int j = 0; j < 4; ++j)
            h[j] = dv[j] * ((float)v[j] + h[j]) + bv[j];
    }
    float4 o = {h[0], h[1], h[2], h[3]};
    *(float4*)&carry[((size_t)b * NCH + c) * DIV + e0] = o;
}

// ---------------- scan pass 2: combine carries, emit cell + h_final -------
__global__ __launch_bounds__(256) void scan_apply(const __hip_bfloat16* __restrict__ xp,
                                                  const float* __restrict__ logd,
                                                  const float* __restrict__ bias,
                                                  const float* __restrict__ h0,
                                                  const float* __restrict__ carry,
                                                  __hip_bfloat16* __restrict__ cell,
                                                  float* __restrict__ hfin) {
    const int eg = blockIdx.x * 256 + threadIdx.x;
    const int e0 = eg * 4;
    const int c = blockIdx.y;
    const int b = blockIdx.z;
    const float4 ld = ((const float4*)logd)[eg];
    const float4 bb = ((const float4*)bias)[eg];
    float dv[4] = {1.f / (1.f + __expf(-ld.x)), 1.f / (1.f + __expf(-ld.y)),
                   1.f / (1.f + __expf(-ld.z)), 1.f / (1.f + __expf(-ld.w))};
    float bv[4] = {bb.x, bb.y, bb.z, bb.w};
    float dCH[4];
#pragma unroll
    for (int j = 0; j < 4; ++j) dCH[j] = __powf(dv[j], (float)CH);

    // H = true h at entry to chunk c (chunk-level recurrence over carries)
    float4 H4 = *(const float4*)&h0[(size_t)b * DIV + e0];
    float H[4] = {H4.x, H4.y, H4.z, H4.w};
    for (int j = 0; j < c; ++j) {
        float4 cr = *(const float4*)&carry[((size_t)b * NCH + j) * DIV + e0];
#pragma unroll
        for (int q = 0; q < 4; ++q) H[q] = dCH[q] * H[q] + ((const float*)&cr)[q];
    }

    const size_t base = ((size_t)(b * TV + c * CH)) * DIV + e0;
    float h[4] = {H[0], H[1], H[2], H[3]};
#pragma unroll 4
    for (int i = 0; i < CH; ++i) {
        bf16x4 v = *(const bf16x4*)(xp + base + (size_t)i * DIV);
        ushort4 o;
        unsigned short* op = (unsigned short*)&o;
#pragma unroll
        for (int j = 0; j < 4; ++j) {
            h[j] = dv[j] * ((float)v[j] + h[j]) + bv[j];
            float cv = h[j] * (h[j] / (1.f + __expf(-h[j])));   // h * silu(h)
            __hip_bfloat16 cb = __float2bfloat16(cv);
            op[j] = *(unsigned short*)&cb;
        }
        *(ushort4*)(cell + base + (size_t)i * DIV) = o;
    }
    if (c == NCH - 1) {
        float4 o = {h[0], h[1], h[2], h[3]};
        *(float4*)&hfin[(size_t)b * DIV + e0] = o;
    }
}

// -------------------------------------------------------------------------
extern "C" void kernel_launch(void* const* d_in, const int* in_sizes, int n_in,
                              void* d_out, int out_size, void* d_ws, size_t ws_size,
                              hipStream_t stream) {
    const float* x     = (const float*)d_in[0];   // [B,T,DIM]
    const float* h0    = (const float*)d_in[1];   // [B,DI]
    const float* W_in  = (const float*)d_in[2];   // [DI,DIM]
    const float* W_out = (const float*)d_in[3];   // [DIM,DI]
    const float* log_d = (const float*)d_in[4];   // [DI]
    const float* bias  = (const float*)d_in[5];   // [DI]

    float* out  = (float*)d_out;                       // [B,T,DIM] fp32
    float* hfin = out + (size_t)BV * TV * DIMV;        // [B,DI] fp32

    // Workspace layout (bytes):
    char* ws = (char*)d_ws;
    __hip_bfloat16* xb    = (__hip_bfloat16*)ws;                          // 64 MiB
    __hip_bfloat16* cellb = xb;                                           // alias: x dead after GEMM1
    __hip_bfloat16* wib   = (__hip_bfloat16*)(ws + 67108864);             // 8 MiB
    __hip_bfloat16* wob   = (__hip_bfloat16*)(ws + 67108864 + 8388608);   // 8 MiB
    __hip_bfloat16* xpb   = (__hip_bfloat16*)(ws + 67108864 + 16777216);  // 64 MiB
    float*          carry = (float*)(ws + 134217728 + 16777216);          // 2 MiB

    // 1) convert inputs to bf16 (single fused kernel)
    {
        int n4 = 10485760;   // 8388608 + 1048576 + 1048576 float4s
        cvt_all<<<n4 / 256, 256, 0, stream>>>((const float4*)x, (const float4*)W_in,
                                              (const float4*)W_out,
                                              (ushort4*)xb, (ushort4*)wib, (ushort4*)wob);
    }

    // 2) GEMM1: xp = silu(x @ W_in^T), bf16 out
    gemm256_bt<1><<<dim3(DIV / 256, MV / 256), 512, 0, stream>>>(xb, wib, nullptr, xpb);

    // 3) scan: chunk carries, then combine + emit cell (bf16) and h_final
    scan_carry<<<dim3(DIV / 1024, NCH, BV), 256, 0, stream>>>(xpb, log_d, bias, carry);
    scan_apply<<<dim3(DIV / 1024, NCH, BV), 256, 0, stream>>>(xpb, log_d, bias, h0, carry, cellb, hfin);

    // 4) GEMM2: out = cell @ W_out^T, fp32 out
    gemm256_bt<0><<<dim3(DIMV / 256, MV / 256), 512, 0, stream>>>(cellb, wob, out, nullptr);
}